// Round 1
// baseline (622.727 us; speedup 1.0000x reference)
//
#include <hip/hip_runtime.h>
#include <stdint.h>

#define N_EXPERTS 8
#define D_MODEL 1024
#define D_FF 4096
#define N_TOKENS 2048
#define ASSN 4096          // N_TOKENS * TOP_K
#define ROWS 4224          // ASSN + 128 slack rows for tile overrun
#define BK 32

using bfrag = __attribute__((ext_vector_type(8))) short;   // 8 x bf16
using f32x4 = __attribute__((ext_vector_type(4))) float;
typedef unsigned short u16;

__device__ __forceinline__ u16 f2bf(float f) {
  uint32_t u = __builtin_bit_cast(uint32_t, f);
  u += 0x7fffu + ((u >> 16) & 1u);   // round-to-nearest-even
  return (u16)(u >> 16);
}

__device__ __forceinline__ void gll16(const void* g, void* l) {
  __builtin_amdgcn_global_load_lds(
      (const __attribute__((address_space(1))) void*)g,
      (__attribute__((address_space(3))) void*)l, 16, 0, 0);
}

// ---------------- setup: bucket assignments by expert ----------------
__global__ void k_setup(const int* __restrict__ eidx, const float* __restrict__ ew,
                        int* __restrict__ rowmap, int* __restrict__ arow,
                        int* __restrict__ counts, int* __restrict__ offs) {
  __shared__ int sc[N_EXPERTS], so[N_EXPERTS];
  int t = threadIdx.x;
  if (t < N_EXPERTS) sc[t] = 0;
  __syncthreads();
  for (int a = t; a < ASSN; a += 256) atomicAdd(&sc[eidx[a]], 1);
  __syncthreads();
  if (t == 0) {
    int run = 0;
    for (int e = 0; e < N_EXPERTS; e++) {
      counts[e] = sc[e]; offs[e] = run; so[e] = run; run += sc[e];
    }
  }
  __syncthreads();
  for (int a = t; a < ASSN; a += 256) {
    int e = eidx[a];
    int p = atomicAdd(&so[e], 1);
    rowmap[p] = a;
    arow[a] = p;
  }
}

// ---------------- gather x rows -> bf16 packed by expert ----------------
__global__ void k_gather(const float* __restrict__ x, const int* __restrict__ rowmap,
                         u16* __restrict__ Xg) {
  int r = blockIdx.x, t = threadIdx.x;
  uint2 o;
  if (r < ASSN) {
    int tok = rowmap[r] >> 1;   // TOP_K = 2
    float4 v = *(const float4*)(x + (size_t)tok * D_MODEL + t * 4);
    o.x = (uint32_t)f2bf(v.x) | ((uint32_t)f2bf(v.y) << 16);
    o.y = (uint32_t)f2bf(v.z) | ((uint32_t)f2bf(v.w) << 16);
  } else {
    o.x = 0u; o.y = 0u;        // zero slack rows
  }
  *(uint2*)(Xg + (size_t)r * D_MODEL + t * 4) = o;
}

// ---- transpose+convert: fp32 [K][N] -> bf16 [N][K], 128k x 64n tiles ----
// Both global sides coalesced in >=256B segments. Tiles per matrix:
// (K/128)*(N/64) == 512 for all three weight shapes.
__global__ void k_convt(const float* __restrict__ src, u16* __restrict__ dst,
                        int K, int N) {
  const int e = blockIdx.y;
  src += (size_t)e * K * N;
  dst += (size_t)e * K * N;
  const int ntn = N >> 6;
  const int n0 = (blockIdx.x % ntn) << 6;
  const int k0 = (blockIdx.x / ntn) << 7;
  __shared__ u16 T[64][136];         // [n][k], stride 272B (16B-aligned rows)
  const int t = threadIdx.x;
  const int rk = t >> 4, rn4 = (t & 15) << 2;
  #pragma unroll
  for (int p = 0; p < 8; p++) {
    const int k = rk + p * 16;
    float4 v = *(const float4*)(src + (size_t)(k0 + k) * N + n0 + rn4);
    T[rn4 + 0][k] = f2bf(v.x);
    T[rn4 + 1][k] = f2bf(v.y);
    T[rn4 + 2][k] = f2bf(v.z);
    T[rn4 + 3][k] = f2bf(v.w);
  }
  __syncthreads();
  const int wn = t >> 4, wk8 = (t & 15) << 3;
  #pragma unroll
  for (int p = 0; p < 4; p++) {
    const int n = wn + p * 16;
    *(bfrag*)(dst + (size_t)(n0 + n) * K + k0 + wk8) = *(const bfrag*)&T[n][wk8];
  }
}

// ---- GEMM1: H = silu(Xg@W1) * (Xg@W2), bf16 weights, all-gll staging ----
__launch_bounds__(256, 2)
__global__ void k_gemm1(const u16* __restrict__ Xg,
                        const u16* __restrict__ w1t, const u16* __restrict__ w2t,
                        const int* __restrict__ counts, const int* __restrict__ offs,
                        u16* __restrict__ H) {
  const int e = blockIdx.z, nt = blockIdx.x, mt = blockIdx.y;
  const int cnt = counts[e];
  if (mt * 128 >= cnt) return;
  const int row0 = offs[e] + mt * 128;
  const int mrem = cnt - mt * 128;
  const int n0 = nt * 128;

  __shared__ u16 As[2][128 * BK];    // 16 KB
  __shared__ u16 B1s[2][128 * BK];   // 16 KB
  __shared__ u16 B2s[2][128 * BK];   // 16 KB

  const int tid = threadIdx.x;
  const int lane = tid & 63, wave = tid >> 6;
  const int wm = (wave >> 1) << 6, wn = (wave & 1) << 6;
  const int l16 = lane & 15, quad = lane >> 4;

  // staging: wave w owns rows [w*32, w*32+32); 2 gll calls of 16 rows each
  const int srow = wave * 32 + (lane >> 2);
  const int scol = (lane & 3) * 8;
  const int ld0 = wave * 1024;               // elems; +512 for call 1

  const u16* pA  = Xg  + (size_t)(row0 + srow) * D_MODEL + scol;
  const u16* pB1 = w1t + (size_t)e * D_MODEL * D_FF + (size_t)(n0 + srow) * D_MODEL + scol;
  const u16* pB2 = w2t + (size_t)e * D_MODEL * D_FF + (size_t)(n0 + srow) * D_MODEL + scol;
  const size_t rstep = (size_t)16 * D_MODEL;

  f32x4 acc1[4][4] = {};
  f32x4 acc2[4][4] = {};

  gll16(pA,          &As[0][ld0]);
  gll16(pA + rstep,  &As[0][ld0 + 512]);
  gll16(pB1,         &B1s[0][ld0]);
  gll16(pB1 + rstep, &B1s[0][ld0 + 512]);
  gll16(pB2,         &B2s[0][ld0]);
  gll16(pB2 + rstep, &B2s[0][ld0 + 512]);
  pA += BK; pB1 += BK; pB2 += BK;
  __syncthreads();

  #pragma unroll 2
  for (int ks = 0; ks < 32; ks++) {
    const int c = ks & 1;
    if (ks < 31) {
      gll16(pA,          &As[1 - c][ld0]);
      gll16(pA + rstep,  &As[1 - c][ld0 + 512]);
      gll16(pB1,         &B1s[1 - c][ld0]);
      gll16(pB1 + rstep, &B1s[1 - c][ld0 + 512]);
      gll16(pB2,         &B2s[1 - c][ld0]);
      gll16(pB2 + rstep, &B2s[1 - c][ld0 + 512]);
      pA += BK; pB1 += BK; pB2 += BK;
    }
    bfrag b1[4], b2[4];
    #pragma unroll
    for (int j = 0; j < 4; j++) {
      b1[j] = *(const bfrag*)&B1s[c][(wn + j * 16 + l16) * BK + quad * 8];
      b2[j] = *(const bfrag*)&B2s[c][(wn + j * 16 + l16) * BK + quad * 8];
    }
    #pragma unroll
    for (int i = 0; i < 4; i++) {
      bfrag a = *(const bfrag*)&As[c][(wm + i * 16 + l16) * BK + quad * 8];
      #pragma unroll
      for (int j = 0; j < 4; j++) {
        acc1[i][j] = __builtin_amdgcn_mfma_f32_16x16x32_bf16(a, b1[j], acc1[i][j], 0, 0, 0);
        acc2[i][j] = __builtin_amdgcn_mfma_f32_16x16x32_bf16(a, b2[j], acc2[i][j], 0, 0, 0);
      }
    }
    __syncthreads();
  }

  // epilogue: h = silu(g)*v, store bf16. C/D layout: col=lane&15, row=quad*4+reg
  #pragma unroll
  for (int i = 0; i < 4; i++) {
    #pragma unroll
    for (int p = 0; p < 4; p++) {
      const int mloc = wm + i * 16 + quad * 4 + p;
      if (mloc < mrem) {
        u16* dst = H + (size_t)(row0 + mloc) * D_FF + n0 + wn + l16;
        #pragma unroll
        for (int j = 0; j < 4; j++) {
          float g = acc1[i][j][p];
          float vv = acc2[i][j][p];
          float h = g / (1.0f + __expf(-g)) * vv;
          dst[j * 16] = f2bf(h);
        }
      }
    }
  }
}

// ---- GEMM2: Y[kh] = H(k-half) @ W3, bf16 weights, split-K x2 ----
__launch_bounds__(256, 2)
__global__ void k_gemm2(const u16* __restrict__ H, const u16* __restrict__ w3t,
                        const int* __restrict__ counts, const int* __restrict__ offs,
                        float* __restrict__ Y0, float* __restrict__ Y1) {
  const int e = blockIdx.z >> 1, khalf = blockIdx.z & 1;
  const int nt = blockIdx.x, mt = blockIdx.y;
  const int cnt = counts[e];
  if (mt * 128 >= cnt) return;
  const int row0 = offs[e] + mt * 128;
  const int mrem = cnt - mt * 128;
  const int n0 = nt * 128;
  float* __restrict__ Y = khalf ? Y1 : Y0;

  __shared__ u16 As[2][128 * BK];
  __shared__ u16 Bs[2][128 * BK];

  const int tid = threadIdx.x;
  const int lane = tid & 63, wave = tid >> 6;
  const int wm = (wave >> 1) << 6, wn = (wave & 1) << 6;
  const int l16 = lane & 15, quad = lane >> 4;

  const int srow = wave * 32 + (lane >> 2);
  const int scol = (lane & 3) * 8;
  const int ld0 = wave * 1024;

  const u16* pA = H + (size_t)(row0 + srow) * D_FF + khalf * 2048 + scol;
  const u16* pB = w3t + (size_t)e * D_FF * D_MODEL
                + (size_t)(n0 + srow) * D_FF + khalf * 2048 + scol;
  const size_t rstepA = (size_t)16 * D_FF;

  f32x4 acc[4][4] = {};

  gll16(pA,           &As[0][ld0]);
  gll16(pA + rstepA,  &As[0][ld0 + 512]);
  gll16(pB,           &Bs[0][ld0]);
  gll16(pB + rstepA,  &Bs[0][ld0 + 512]);
  pA += BK; pB += BK;
  __syncthreads();

  #pragma unroll 2
  for (int ks = 0; ks < 64; ks++) {
    const int c = ks & 1;
    if (ks < 63) {
      gll16(pA,          &As[1 - c][ld0]);
      gll16(pA + rstepA, &As[1 - c][ld0 + 512]);
      gll16(pB,          &Bs[1 - c][ld0]);
      gll16(pB + rstepA, &Bs[1 - c][ld0 + 512]);
      pA += BK; pB += BK;
    }
    bfrag b[4];
    #pragma unroll
    for (int j = 0; j < 4; j++)
      b[j] = *(const bfrag*)&Bs[c][(wn + j * 16 + l16) * BK + quad * 8];
    #pragma unroll
    for (int i = 0; i < 4; i++) {
      bfrag a = *(const bfrag*)&As[c][(wm + i * 16 + l16) * BK + quad * 8];
      #pragma unroll
      for (int j = 0; j < 4; j++)
        acc[i][j] = __builtin_amdgcn_mfma_f32_16x16x32_bf16(a, b[j], acc[i][j], 0, 0, 0);
    }
    __syncthreads();
  }

  #pragma unroll
  for (int i = 0; i < 4; i++) {
    #pragma unroll
    for (int p = 0; p < 4; p++) {
      const int mloc = wm + i * 16 + quad * 4 + p;
      if (mloc < mrem) {
        float* dst = Y + (size_t)(row0 + mloc) * D_MODEL + n0 + wn + l16;
        #pragma unroll
        for (int j = 0; j < 4; j++) dst[j * 16] = acc[i][j][p];
      }
    }
  }
}

// ---------------- combine: out[tok] = sum_j w_j * (Y0+Y1)[arow] ----------
__global__ void k_combine(const float* __restrict__ Y0, const float* __restrict__ Y1,
                          const int* __restrict__ arow, const float* __restrict__ ew,
                          float* __restrict__ out) {
  const int tk = blockIdx.x;
  const int d = threadIdx.x * 4;
  const int a0 = tk * 2, a1 = tk * 2 + 1;
  const int r0 = arow[a0], r1 = arow[a1];
  const float w0 = ew[a0], w1 = ew[a1];
  const float4 p0 = *(const float4*)(Y0 + (size_t)r0 * D_MODEL + d);
  const float4 q0 = *(const float4*)(Y1 + (size_t)r0 * D_MODEL + d);
  const float4 p1 = *(const float4*)(Y0 + (size_t)r1 * D_MODEL + d);
  const float4 q1 = *(const float4*)(Y1 + (size_t)r1 * D_MODEL + d);
  float4 r;
  r.x = w0 * (p0.x + q0.x) + w1 * (p1.x + q1.x);
  r.y = w0 * (p0.y + q0.y) + w1 * (p1.y + q1.y);
  r.z = w0 * (p0.z + q0.z) + w1 * (p1.z + q1.z);
  r.w = w0 * (p0.w + q0.w) + w1 * (p1.w + q1.w);
  *(float4*)(out + (size_t)tk * D_MODEL + d) = r;
}

// ---------------- launcher ----------------
extern "C" void kernel_launch(void* const* d_in, const int* in_sizes, int n_in,
                              void* d_out, int out_size, void* d_ws, size_t ws_size,
                              hipStream_t stream) {
  const float* x  = (const float*)d_in[0];
  const int* eidx = (const int*)d_in[1];
  const float* ew = (const float*)d_in[2];
  const float* w1 = (const float*)d_in[3];
  const float* w2 = (const float*)d_in[4];
  const float* w3 = (const float*)d_in[5];
  float* out = (float*)d_out;

  char* ws = (char*)d_ws;
  int*   rowmap = (int*)(ws);
  int*   arow   = (int*)(ws + 16384);
  int*   counts = (int*)(ws + 32768);
  int*   offs   = (int*)(ws + 32768 + 64);
  const size_t D0 = 65536;
  const size_t SZ_XG = (size_t)ROWS * D_MODEL * 2;            //  8,650,752
  const size_t SZ_HB = (size_t)ROWS * D_FF * 2;               // 34,603,008
  const size_t SZ_Y  = (size_t)ROWS * D_MODEL * 4;            // 17,301,504
  const size_t SZ_W  = (size_t)N_EXPERTS * D_MODEL * D_FF * 2; // 67,108,864
  u16*   Xg  = (u16*)(ws + D0);
  u16*   Hb  = (u16*)(ws + D0 + SZ_XG);
  float* Y0  = (float*)(ws + D0 + SZ_XG + SZ_HB);
  float* Y1  = (float*)(ws + D0 + SZ_XG + SZ_HB + SZ_Y);
  u16*   wt1 = (u16*)(ws + D0 + SZ_XG + SZ_HB + 2 * SZ_Y);
  u16*   wt2 = wt1 + SZ_W / 2;
  u16*   wt3 = wt1;   // aliases wt1: w1t is dead once k_gemm1 completes
  // total ws use ~212 MB

  k_setup<<<1, 256, 0, stream>>>(eidx, ew, rowmap, arow, counts, offs);
  k_gather<<<ROWS, 256, 0, stream>>>(x, rowmap, Xg);
  // pre-convert weights fp32 [K][N] -> bf16 [N][K] (transposed) so GEMMs
  // can stage B with global_load_lds (linear LDS dest) and keep the
  // K-loop free of VALU conversion work.
  k_convt<<<dim3(512, N_EXPERTS), 256, 0, stream>>>(w1, wt1, D_MODEL, D_FF);
  k_convt<<<dim3(512, N_EXPERTS), 256, 0, stream>>>(w2, wt2, D_MODEL, D_FF);
  // nt-major grids: blocks sharing a weight slice differ by a multiple of 8
  // in linear index -> same XCD -> weight re-reads are L2 hits.
  k_gemm1<<<dim3(D_FF / 128, 32, N_EXPERTS), 256, 0, stream>>>(Xg, wt1, wt2, counts, offs, Hb);
  k_convt<<<dim3(512, N_EXPERTS), 256, 0, stream>>>(w3, wt3, D_FF, D_MODEL);
  k_gemm2<<<dim3(D_MODEL / 128, 32, N_EXPERTS * 2), 256, 0, stream>>>(Hb, wt3, counts, offs, Y0, Y1);
  k_combine<<<N_TOKENS, 256, 0, stream>>>(Y0, Y1, arow, ew, out);
}

// Round 2
// 614.460 us; speedup vs baseline: 1.0135x; 1.0135x over previous
//
#include <hip/hip_runtime.h>
#include <stdint.h>

#define N_EXPERTS 8
#define D_MODEL 1024
#define D_FF 4096
#define N_TOKENS 2048
#define ASSN 4096          // N_TOKENS * TOP_K
#define ROWS 4224          // ASSN + 128 slack rows for tile overrun
#define BK 32

using bfrag = __attribute__((ext_vector_type(8))) short;   // 8 x bf16
using f32x4 = __attribute__((ext_vector_type(4))) float;
typedef unsigned short u16;

__device__ __forceinline__ u16 f2bf(float f) {
  uint32_t u = __builtin_bit_cast(uint32_t, f);
  u += 0x7fffu + ((u >> 16) & 1u);   // round-to-nearest-even
  return (u16)(u >> 16);
}

__device__ __forceinline__ void gll16(const void* g, void* l) {
  __builtin_amdgcn_global_load_lds(
      (const __attribute__((address_space(1))) void*)g,
      (__attribute__((address_space(3))) void*)l, 16, 0, 0);
}

// ---------------- setup: bucket assignments by expert ----------------
__global__ void k_setup(const int* __restrict__ eidx, const float* __restrict__ ew,
                        int* __restrict__ rowmap, int* __restrict__ arow,
                        int* __restrict__ counts, int* __restrict__ offs) {
  __shared__ int sc[N_EXPERTS], so[N_EXPERTS];
  int t = threadIdx.x;
  if (t < N_EXPERTS) sc[t] = 0;
  __syncthreads();
  for (int a = t; a < ASSN; a += 256) atomicAdd(&sc[eidx[a]], 1);
  __syncthreads();
  if (t == 0) {
    int run = 0;
    for (int e = 0; e < N_EXPERTS; e++) {
      counts[e] = sc[e]; offs[e] = run; so[e] = run; run += sc[e];
    }
  }
  __syncthreads();
  for (int a = t; a < ASSN; a += 256) {
    int e = eidx[a];
    int p = atomicAdd(&so[e], 1);
    rowmap[p] = a;
    arow[a] = p;
  }
}

// ---------------- gather x rows -> bf16 packed by expert ----------------
__global__ void k_gather(const float* __restrict__ x, const int* __restrict__ rowmap,
                         u16* __restrict__ Xg) {
  int r = blockIdx.x, t = threadIdx.x;
  uint2 o;
  if (r < ASSN) {
    int tok = rowmap[r] >> 1;   // TOP_K = 2
    float4 v = *(const float4*)(x + (size_t)tok * D_MODEL + t * 4);
    o.x = (uint32_t)f2bf(v.x) | ((uint32_t)f2bf(v.y) << 16);
    o.y = (uint32_t)f2bf(v.z) | ((uint32_t)f2bf(v.w) << 16);
  } else {
    o.x = 0u; o.y = 0u;        // zero slack rows
  }
  *(uint2*)(Xg + (size_t)r * D_MODEL + t * 4) = o;
}

// ---- transpose+convert: fp32 [K][N] -> bf16 [N][K], 64k x 64n tiles ----
// LDS holds u32 k-pairs at stride 33 (odd): write banks = (4i+c+kp) mod 32
// and read banks = (n+8*seg+j) mod 32 are both exactly 2 lanes/bank = free.
__global__ void k_convt(const float* __restrict__ src, u16* __restrict__ dst,
                        int K, int N) {
  const int e = blockIdx.y;
  src += (size_t)e * K * N;
  dst += (size_t)e * K * N;
  const int ntn = N >> 6;
  const int n0 = (blockIdx.x % ntn) << 6;
  const int k0 = (blockIdx.x / ntn) << 6;
  __shared__ uint32_t T2[64 * 33];
  const int t = threadIdx.x;
  const int i4 = (t & 15) << 2;      // n base within tile
  const int q  = t >> 4;             // k-pair row 0..15
  #pragma unroll
  for (int p = 0; p < 2; p++) {
    const int kp = q + (p << 4);
    const float4 r0 = *(const float4*)(src + (size_t)(k0 + 2 * kp    ) * N + n0 + i4);
    const float4 r1 = *(const float4*)(src + (size_t)(k0 + 2 * kp + 1) * N + n0 + i4);
    T2[(i4 + 0) * 33 + kp] = (uint32_t)f2bf(r0.x) | ((uint32_t)f2bf(r1.x) << 16);
    T2[(i4 + 1) * 33 + kp] = (uint32_t)f2bf(r0.y) | ((uint32_t)f2bf(r1.y) << 16);
    T2[(i4 + 2) * 33 + kp] = (uint32_t)f2bf(r0.z) | ((uint32_t)f2bf(r1.z) << 16);
    T2[(i4 + 3) * 33 + kp] = (uint32_t)f2bf(r0.w) | ((uint32_t)f2bf(r1.w) << 16);
  }
  __syncthreads();
  const int n = t >> 2, seg = t & 3;
  uint32_t w[8];
  #pragma unroll
  for (int j = 0; j < 8; j++) w[j] = T2[n * 33 + (seg << 3) + j];
  u16* d = dst + (size_t)(n0 + n) * K + k0 + (seg << 4);
  *(uint4*)d = *(uint4*)&w[0];
  *(uint4*)(d + 8) = *(uint4*)&w[4];
}

// ---- GEMM1: H = silu(Xg@W1) * (Xg@W2), counted-vmcnt dbuf pipeline ----
__launch_bounds__(256, 2)
__global__ void k_gemm1(const u16* __restrict__ Xg,
                        const u16* __restrict__ w1t, const u16* __restrict__ w2t,
                        const int* __restrict__ counts, const int* __restrict__ offs,
                        u16* __restrict__ H) {
  const int e = blockIdx.z, nt = blockIdx.x, mt = blockIdx.y;
  const int cnt = counts[e];
  if (mt * 128 >= cnt) return;
  const int row0 = offs[e] + mt * 128;
  const int mrem = cnt - mt * 128;
  const int n0 = nt * 128;

  __shared__ u16 As[2][128 * BK];    // 16 KB
  __shared__ u16 B1s[2][128 * BK];   // 16 KB
  __shared__ u16 B2s[2][128 * BK];   // 16 KB

  const int tid = threadIdx.x;
  const int lane = tid & 63, wave = tid >> 6;
  const int wm = (wave >> 1) << 6, wn = (wave & 1) << 6;
  const int l16 = lane & 15, quad = lane >> 4;

  // staging: wave w owns rows [w*32, w*32+32); 2 gll calls of 16 rows each
  const int srow = wave * 32 + (lane >> 2);
  const int scol = (lane & 3) * 8;
  const int ld0 = wave * 1024;               // elems; +512 for call 1

  const u16* pA  = Xg  + (size_t)(row0 + srow) * D_MODEL + scol;
  const u16* pB1 = w1t + (size_t)e * D_MODEL * D_FF + (size_t)(n0 + srow) * D_MODEL + scol;
  const u16* pB2 = w2t + (size_t)e * D_MODEL * D_FF + (size_t)(n0 + srow) * D_MODEL + scol;
  const size_t rstep = (size_t)16 * D_MODEL;

  f32x4 acc1[4][4] = {};
  f32x4 acc2[4][4] = {};

  // prologue: issue stage of K-step 0 into buf0 (no drain)
  gll16(pA,          &As[0][ld0]);
  gll16(pA + rstep,  &As[0][ld0 + 512]);
  gll16(pB1,         &B1s[0][ld0]);
  gll16(pB1 + rstep, &B1s[0][ld0 + 512]);
  gll16(pB2,         &B2s[0][ld0]);
  gll16(pB2 + rstep, &B2s[0][ld0 + 512]);
  pA += BK; pB1 += BK; pB2 += BK;

  #pragma unroll 2
  for (int ks = 0; ks < 32; ks++) {
    const int c = ks & 1;
    if (ks < 31) {
      // issue stage of step ks+1; keep it in flight across the barriers
      gll16(pA,          &As[1 - c][ld0]);
      gll16(pA + rstep,  &As[1 - c][ld0 + 512]);
      gll16(pB1,         &B1s[1 - c][ld0]);
      gll16(pB1 + rstep, &B1s[1 - c][ld0 + 512]);
      gll16(pB2,         &B2s[1 - c][ld0]);
      gll16(pB2 + rstep, &B2s[1 - c][ld0 + 512]);
      pA += BK; pB1 += BK; pB2 += BK;
      asm volatile("s_waitcnt vmcnt(6)" ::: "memory");   // step ks landed
    } else {
      asm volatile("s_waitcnt vmcnt(0)" ::: "memory");
    }
    __builtin_amdgcn_sched_barrier(0);
    __builtin_amdgcn_s_barrier();                        // all waves: buf[c] ready
    __builtin_amdgcn_sched_barrier(0);

    bfrag b1[4], b2[4];
    #pragma unroll
    for (int j = 0; j < 4; j++) {
      b1[j] = *(const bfrag*)&B1s[c][(wn + j * 16 + l16) * BK + quad * 8];
      b2[j] = *(const bfrag*)&B2s[c][(wn + j * 16 + l16) * BK + quad * 8];
    }
    #pragma unroll
    for (int i = 0; i < 4; i++) {
      bfrag a = *(const bfrag*)&As[c][(wm + i * 16 + l16) * BK + quad * 8];
      #pragma unroll
      for (int j = 0; j < 4; j++) {
        acc1[i][j] = __builtin_amdgcn_mfma_f32_16x16x32_bf16(a, b1[j], acc1[i][j], 0, 0, 0);
        acc2[i][j] = __builtin_amdgcn_mfma_f32_16x16x32_bf16(a, b2[j], acc2[i][j], 0, 0, 0);
      }
    }
    __builtin_amdgcn_sched_barrier(0);
    asm volatile("s_waitcnt lgkmcnt(0)" ::: "memory");   // reads of buf[c] done
    __builtin_amdgcn_s_barrier();                        // safe to overwrite buf[c]
    __builtin_amdgcn_sched_barrier(0);
  }

  // epilogue: h = silu(g)*v, store bf16. C/D layout: col=lane&15, row=quad*4+reg
  #pragma unroll
  for (int i = 0; i < 4; i++) {
    #pragma unroll
    for (int p = 0; p < 4; p++) {
      const int mloc = wm + i * 16 + quad * 4 + p;
      if (mloc < mrem) {
        u16* dst = H + (size_t)(row0 + mloc) * D_FF + n0 + wn + l16;
        #pragma unroll
        for (int j = 0; j < 4; j++) {
          float g = acc1[i][j][p];
          float vv = acc2[i][j][p];
          float h = g / (1.0f + __expf(-g)) * vv;
          dst[j * 16] = f2bf(h);
        }
      }
    }
  }
}

// ---- GEMM2: Y[kh] = H(k-half) @ W3, counted-vmcnt, split-K x2 ----
__launch_bounds__(256, 2)
__global__ void k_gemm2(const u16* __restrict__ H, const u16* __restrict__ w3t,
                        const int* __restrict__ counts, const int* __restrict__ offs,
                        float* __restrict__ Y0, float* __restrict__ Y1) {
  const int e = blockIdx.z >> 1, khalf = blockIdx.z & 1;
  const int nt = blockIdx.x, mt = blockIdx.y;
  const int cnt = counts[e];
  if (mt * 128 >= cnt) return;
  const int row0 = offs[e] + mt * 128;
  const int mrem = cnt - mt * 128;
  const int n0 = nt * 128;
  float* __restrict__ Y = khalf ? Y1 : Y0;

  __shared__ u16 As[2][128 * BK];
  __shared__ u16 Bs[2][128 * BK];

  const int tid = threadIdx.x;
  const int lane = tid & 63, wave = tid >> 6;
  const int wm = (wave >> 1) << 6, wn = (wave & 1) << 6;
  const int l16 = lane & 15, quad = lane >> 4;

  const int srow = wave * 32 + (lane >> 2);
  const int scol = (lane & 3) * 8;
  const int ld0 = wave * 1024;

  const u16* pA = H + (size_t)(row0 + srow) * D_FF + khalf * 2048 + scol;
  const u16* pB = w3t + (size_t)e * D_FF * D_MODEL
                + (size_t)(n0 + srow) * D_FF + khalf * 2048 + scol;
  const size_t rstepA = (size_t)16 * D_FF;

  f32x4 acc[4][4] = {};

  gll16(pA,           &As[0][ld0]);
  gll16(pA + rstepA,  &As[0][ld0 + 512]);
  gll16(pB,           &Bs[0][ld0]);
  gll16(pB + rstepA,  &Bs[0][ld0 + 512]);
  pA += BK; pB += BK;

  #pragma unroll 2
  for (int ks = 0; ks < 64; ks++) {
    const int c = ks & 1;
    if (ks < 63) {
      gll16(pA,          &As[1 - c][ld0]);
      gll16(pA + rstepA, &As[1 - c][ld0 + 512]);
      gll16(pB,          &Bs[1 - c][ld0]);
      gll16(pB + rstepA, &Bs[1 - c][ld0 + 512]);
      pA += BK; pB += BK;
      asm volatile("s_waitcnt vmcnt(4)" ::: "memory");
    } else {
      asm volatile("s_waitcnt vmcnt(0)" ::: "memory");
    }
    __builtin_amdgcn_sched_barrier(0);
    __builtin_amdgcn_s_barrier();
    __builtin_amdgcn_sched_barrier(0);

    bfrag b[4];
    #pragma unroll
    for (int j = 0; j < 4; j++)
      b[j] = *(const bfrag*)&Bs[c][(wn + j * 16 + l16) * BK + quad * 8];
    #pragma unroll
    for (int i = 0; i < 4; i++) {
      bfrag a = *(const bfrag*)&As[c][(wm + i * 16 + l16) * BK + quad * 8];
      #pragma unroll
      for (int j = 0; j < 4; j++)
        acc[i][j] = __builtin_amdgcn_mfma_f32_16x16x32_bf16(a, b[j], acc[i][j], 0, 0, 0);
    }
    __builtin_amdgcn_sched_barrier(0);
    asm volatile("s_waitcnt lgkmcnt(0)" ::: "memory");
    __builtin_amdgcn_s_barrier();
    __builtin_amdgcn_sched_barrier(0);
  }

  #pragma unroll
  for (int i = 0; i < 4; i++) {
    #pragma unroll
    for (int p = 0; p < 4; p++) {
      const int mloc = wm + i * 16 + quad * 4 + p;
      if (mloc < mrem) {
        float* dst = Y + (size_t)(row0 + mloc) * D_MODEL + n0 + wn + l16;
        #pragma unroll
        for (int j = 0; j < 4; j++) dst[j * 16] = acc[i][j][p];
      }
    }
  }
}

// ---------------- combine: out[tok] = sum_j w_j * (Y0+Y1)[arow] ----------
__global__ void k_combine(const float* __restrict__ Y0, const float* __restrict__ Y1,
                          const int* __restrict__ arow, const float* __restrict__ ew,
                          float* __restrict__ out) {
  const int tk = blockIdx.x;
  const int d = threadIdx.x * 4;
  const int a0 = tk * 2, a1 = tk * 2 + 1;
  const int r0 = arow[a0], r1 = arow[a1];
  const float w0 = ew[a0], w1 = ew[a1];
  const float4 p0 = *(const float4*)(Y0 + (size_t)r0 * D_MODEL + d);
  const float4 q0 = *(const float4*)(Y1 + (size_t)r0 * D_MODEL + d);
  const float4 p1 = *(const float4*)(Y0 + (size_t)r1 * D_MODEL + d);
  const float4 q1 = *(const float4*)(Y1 + (size_t)r1 * D_MODEL + d);
  float4 r;
  r.x = w0 * (p0.x + q0.x) + w1 * (p1.x + q1.x);
  r.y = w0 * (p0.y + q0.y) + w1 * (p1.y + q1.y);
  r.z = w0 * (p0.z + q0.z) + w1 * (p1.z + q1.z);
  r.w = w0 * (p0.w + q0.w) + w1 * (p1.w + q1.w);
  *(float4*)(out + (size_t)tk * D_MODEL + d) = r;
}

// ---------------- launcher ----------------
extern "C" void kernel_launch(void* const* d_in, const int* in_sizes, int n_in,
                              void* d_out, int out_size, void* d_ws, size_t ws_size,
                              hipStream_t stream) {
  const float* x  = (const float*)d_in[0];
  const int* eidx = (const int*)d_in[1];
  const float* ew = (const float*)d_in[2];
  const float* w1 = (const float*)d_in[3];
  const float* w2 = (const float*)d_in[4];
  const float* w3 = (const float*)d_in[5];
  float* out = (float*)d_out;

  char* ws = (char*)d_ws;
  int*   rowmap = (int*)(ws);
  int*   arow   = (int*)(ws + 16384);
  int*   counts = (int*)(ws + 32768);
  int*   offs   = (int*)(ws + 32768 + 64);
  const size_t D0 = 65536;
  const size_t SZ_XG = (size_t)ROWS * D_MODEL * 2;            //  8,650,752
  const size_t SZ_HB = (size_t)ROWS * D_FF * 2;               // 34,603,008
  const size_t SZ_Y  = (size_t)ROWS * D_MODEL * 4;            // 17,301,504
  const size_t SZ_W  = (size_t)N_EXPERTS * D_MODEL * D_FF * 2; // 67,108,864
  u16*   Xg  = (u16*)(ws + D0);
  u16*   Hb  = (u16*)(ws + D0 + SZ_XG);
  float* Y0  = (float*)(ws + D0 + SZ_XG + SZ_HB);
  float* Y1  = (float*)(ws + D0 + SZ_XG + SZ_HB + SZ_Y);
  u16*   wt1 = (u16*)(ws + D0 + SZ_XG + SZ_HB + 2 * SZ_Y);
  u16*   wt2 = wt1 + SZ_W / 2;
  u16*   wt3 = wt1;   // aliases wt1: w1t is dead once k_gemm1 completes
  // total ws use ~212 MB

  k_setup<<<1, 256, 0, stream>>>(eidx, ew, rowmap, arow, counts, offs);
  k_gather<<<ROWS, 256, 0, stream>>>(x, rowmap, Xg);
  // pre-convert weights fp32 [K][N] -> bf16 [N][K] (transposed) so GEMMs
  // can stage B with global_load_lds and keep the K-loop free of VALU work.
  k_convt<<<dim3(1024, N_EXPERTS), 256, 0, stream>>>(w1, wt1, D_MODEL, D_FF);
  k_convt<<<dim3(1024, N_EXPERTS), 256, 0, stream>>>(w2, wt2, D_MODEL, D_FF);
  // nt-major grids: blocks sharing a weight slice differ by a multiple of 8
  // in linear index -> same XCD -> weight re-reads are L2 hits.
  k_gemm1<<<dim3(D_FF / 128, 32, N_EXPERTS), 256, 0, stream>>>(Xg, wt1, wt2, counts, offs, Hb);
  k_convt<<<dim3(1024, N_EXPERTS), 256, 0, stream>>>(w3, wt3, D_FF, D_MODEL);
  k_gemm2<<<dim3(D_MODEL / 128, 32, N_EXPERTS * 2), 256, 0, stream>>>(Hb, wt3, counts, offs, Y0, Y1);
  k_combine<<<N_TOKENS, 256, 0, stream>>>(Y0, Y1, arow, ew, out);
}

// Round 4
// 612.781 us; speedup vs baseline: 1.0162x; 1.0027x over previous
//
#include <hip/hip_runtime.h>
#include <stdint.h>

#define N_EXPERTS 8
#define D_MODEL 1024
#define D_FF 4096
#define N_TOKENS 2048
#define ASSN 4096          // N_TOKENS * TOP_K
#define ROWS 4224          // ASSN + 128 slack rows for tile overrun
#define BK 32

using bfrag = __attribute__((ext_vector_type(8))) short;   // 8 x bf16
using f32x4 = __attribute__((ext_vector_type(4))) float;
typedef unsigned short u16;

__device__ __forceinline__ u16 f2bf(float f) {
  uint32_t u = __builtin_bit_cast(uint32_t, f);
  u += 0x7fffu + ((u >> 16) & 1u);   // round-to-nearest-even
  return (u16)(u >> 16);
}

__device__ __forceinline__ void gll16(const void* g, void* l) {
  __builtin_amdgcn_global_load_lds(
      (const __attribute__((address_space(1))) void*)g,
      (__attribute__((address_space(3))) void*)l, 16, 0, 0);
}

// ---------------- setup: bucket assignments by expert ----------------
__global__ void k_setup(const int* __restrict__ eidx, const float* __restrict__ ew,
                        int* __restrict__ rowmap, int* __restrict__ arow,
                        int* __restrict__ counts, int* __restrict__ offs) {
  __shared__ int sc[N_EXPERTS], so[N_EXPERTS];
  int t = threadIdx.x;
  if (t < N_EXPERTS) sc[t] = 0;
  __syncthreads();
  for (int a = t; a < ASSN; a += 256) atomicAdd(&sc[eidx[a]], 1);
  __syncthreads();
  if (t == 0) {
    int run = 0;
    for (int e = 0; e < N_EXPERTS; e++) {
      counts[e] = sc[e]; offs[e] = run; so[e] = run; run += sc[e];
    }
  }
  __syncthreads();
  for (int a = t; a < ASSN; a += 256) {
    int e = eidx[a];
    int p = atomicAdd(&so[e], 1);
    rowmap[p] = a;
    arow[a] = p;
  }
}

// ---------------- gather x rows -> bf16 packed by expert ----------------
__global__ void k_gather(const float* __restrict__ x, const int* __restrict__ rowmap,
                         u16* __restrict__ Xg) {
  int r = blockIdx.x, t = threadIdx.x;
  uint2 o;
  if (r < ASSN) {
    int tok = rowmap[r] >> 1;   // TOP_K = 2
    float4 v = *(const float4*)(x + (size_t)tok * D_MODEL + t * 4);
    o.x = (uint32_t)f2bf(v.x) | ((uint32_t)f2bf(v.y) << 16);
    o.y = (uint32_t)f2bf(v.z) | ((uint32_t)f2bf(v.w) << 16);
  } else {
    o.x = 0u; o.y = 0u;        // zero slack rows
  }
  *(uint2*)(Xg + (size_t)r * D_MODEL + t * 4) = o;
}

// ---- transpose+convert: fp32 [K][N] -> bf16 [N][K], 64k x 64n tiles ----
// LDS holds u32 k-pairs at stride 33 (odd): write banks = (4i+c+kp) mod 32
// and read banks = (n+8*seg+j) mod 32 are both exactly 2 lanes/bank = free.
__global__ void k_convt(const float* __restrict__ src, u16* __restrict__ dst,
                        int K, int N) {
  const int e = blockIdx.y;
  src += (size_t)e * K * N;
  dst += (size_t)e * K * N;
  const int ntn = N >> 6;
  const int n0 = (blockIdx.x % ntn) << 6;
  const int k0 = (blockIdx.x / ntn) << 6;
  __shared__ uint32_t T2[64 * 33];
  const int t = threadIdx.x;
  const int i4 = (t & 15) << 2;      // n base within tile
  const int q  = t >> 4;             // k-pair row 0..15
  #pragma unroll
  for (int p = 0; p < 2; p++) {
    const int kp = q + (p << 4);
    const float4 r0 = *(const float4*)(src + (size_t)(k0 + 2 * kp    ) * N + n0 + i4);
    const float4 r1 = *(const float4*)(src + (size_t)(k0 + 2 * kp + 1) * N + n0 + i4);
    T2[(i4 + 0) * 33 + kp] = (uint32_t)f2bf(r0.x) | ((uint32_t)f2bf(r1.x) << 16);
    T2[(i4 + 1) * 33 + kp] = (uint32_t)f2bf(r0.y) | ((uint32_t)f2bf(r1.y) << 16);
    T2[(i4 + 2) * 33 + kp] = (uint32_t)f2bf(r0.z) | ((uint32_t)f2bf(r1.z) << 16);
    T2[(i4 + 3) * 33 + kp] = (uint32_t)f2bf(r0.w) | ((uint32_t)f2bf(r1.w) << 16);
  }
  __syncthreads();
  const int n = t >> 2, seg = t & 3;
  uint32_t w[8];
  #pragma unroll
  for (int j = 0; j < 8; j++) w[j] = T2[n * 33 + (seg << 3) + j];
  u16* d = dst + (size_t)(n0 + n) * K + k0 + (seg << 4);
  *(uint4*)d = *(uint4*)&w[0];
  *(uint4*)(d + 8) = *(uint4*)&w[4];
}

// ---- GEMM1: H = silu(Xg@W1) * (Xg@W2), swizzled LDS, counted vmcnt ----
// LDS k-slot swizzle: physical slot = logical slot ^ ((row>>1)&3).
// Write side (gll16 is linear): lane l pre-swizzles its GLOBAL k-seg.
// Read side: slot = quad ^ ((l16>>1)&3). Per 16-lane quad the bank base
// 16*(l16&1) + 4*(quad^v) covers all 32 banks with exactly 2 lanes each.
__launch_bounds__(256, 2)
__global__ void k_gemm1(const u16* __restrict__ Xg,
                        const u16* __restrict__ w1t, const u16* __restrict__ w2t,
                        const int* __restrict__ counts, const int* __restrict__ offs,
                        u16* __restrict__ H) {
  const int e = blockIdx.z, nt = blockIdx.x, mt = blockIdx.y;
  const int cnt = counts[e];
  if (mt * 128 >= cnt) return;
  const int row0 = offs[e] + mt * 128;
  const int mrem = cnt - mt * 128;
  const int n0 = nt * 128;

  __shared__ u16 As[2][128 * BK];    // 16 KB
  __shared__ u16 B1s[2][128 * BK];   // 16 KB
  __shared__ u16 B2s[2][128 * BK];   // 16 KB

  const int tid = threadIdx.x;
  const int lane = tid & 63, wave = tid >> 6;
  const int wm = (wave >> 1) << 6, wn = (wave & 1) << 6;
  const int l16 = lane & 15, quad = lane >> 4;

  // staging: wave w owns rows [w*32, w*32+32); 2 gll calls of 16 rows each
  const int srow = wave * 32 + (lane >> 2);
  const int scol = (((lane & 3) ^ ((lane >> 3) & 3)) << 3);  // pre-swizzled k-seg
  const int ld0 = wave * 1024;               // elems; +512 for call 1

  const u16* pA  = Xg  + (size_t)(row0 + srow) * D_MODEL + scol;
  const u16* pB1 = w1t + (size_t)e * D_MODEL * D_FF + (size_t)(n0 + srow) * D_MODEL + scol;
  const u16* pB2 = w2t + (size_t)e * D_MODEL * D_FF + (size_t)(n0 + srow) * D_MODEL + scol;
  const size_t rstep = (size_t)16 * D_MODEL;

  // swizzled read k-slot (loop-invariant)
  const int rslot = ((quad ^ ((l16 >> 1) & 3)) << 3);

  f32x4 acc1[4][4] = {};
  f32x4 acc2[4][4] = {};

  // prologue: issue stage of K-step 0 into buf0 (no drain)
  gll16(pA,          &As[0][ld0]);
  gll16(pA + rstep,  &As[0][ld0 + 512]);
  gll16(pB1,         &B1s[0][ld0]);
  gll16(pB1 + rstep, &B1s[0][ld0 + 512]);
  gll16(pB2,         &B2s[0][ld0]);
  gll16(pB2 + rstep, &B2s[0][ld0 + 512]);
  pA += BK; pB1 += BK; pB2 += BK;

  #pragma unroll 2
  for (int ks = 0; ks < 32; ks++) {
    const int c = ks & 1;
    if (ks < 31) {
      // issue stage of step ks+1; keep it in flight across the barriers
      gll16(pA,          &As[1 - c][ld0]);
      gll16(pA + rstep,  &As[1 - c][ld0 + 512]);
      gll16(pB1,         &B1s[1 - c][ld0]);
      gll16(pB1 + rstep, &B1s[1 - c][ld0 + 512]);
      gll16(pB2,         &B2s[1 - c][ld0]);
      gll16(pB2 + rstep, &B2s[1 - c][ld0 + 512]);
      pA += BK; pB1 += BK; pB2 += BK;
      asm volatile("s_waitcnt vmcnt(6)" ::: "memory");   // step ks landed
    } else {
      asm volatile("s_waitcnt vmcnt(0)" ::: "memory");
    }
    __builtin_amdgcn_sched_barrier(0);
    __builtin_amdgcn_s_barrier();                        // all waves: buf[c] ready
    __builtin_amdgcn_sched_barrier(0);

    bfrag b1[4], b2[4];
    #pragma unroll
    for (int j = 0; j < 4; j++) {
      b1[j] = *(const bfrag*)&B1s[c][(wn + j * 16 + l16) * BK + rslot];
      b2[j] = *(const bfrag*)&B2s[c][(wn + j * 16 + l16) * BK + rslot];
    }
    #pragma unroll
    for (int i = 0; i < 4; i++) {
      bfrag a = *(const bfrag*)&As[c][(wm + i * 16 + l16) * BK + rslot];
      #pragma unroll
      for (int j = 0; j < 4; j++) {
        acc1[i][j] = __builtin_amdgcn_mfma_f32_16x16x32_bf16(a, b1[j], acc1[i][j], 0, 0, 0);
        acc2[i][j] = __builtin_amdgcn_mfma_f32_16x16x32_bf16(a, b2[j], acc2[i][j], 0, 0, 0);
      }
    }
    __builtin_amdgcn_sched_barrier(0);
    asm volatile("s_waitcnt lgkmcnt(0)" ::: "memory");   // reads of buf[c] done
    __builtin_amdgcn_s_barrier();                        // safe to overwrite buf[c]
    __builtin_amdgcn_sched_barrier(0);
  }

  // epilogue: h = silu(g)*v, store bf16. C/D layout: col=lane&15, row=quad*4+reg
  #pragma unroll
  for (int i = 0; i < 4; i++) {
    #pragma unroll
    for (int p = 0; p < 4; p++) {
      const int mloc = wm + i * 16 + quad * 4 + p;
      if (mloc < mrem) {
        u16* dst = H + (size_t)(row0 + mloc) * D_FF + n0 + wn + l16;
        #pragma unroll
        for (int j = 0; j < 4; j++) {
          float g = acc1[i][j][p];
          float vv = acc2[i][j][p];
          float h = g / (1.0f + __expf(-g)) * vv;
          dst[j * 16] = f2bf(h);
        }
      }
    }
  }
}

// ---- GEMM2: Y[kh] = H(k-half) @ W3, swizzled LDS, split-K x2 ----
__launch_bounds__(256, 2)
__global__ void k_gemm2(const u16* __restrict__ H, const u16* __restrict__ w3t,
                        const int* __restrict__ counts, const int* __restrict__ offs,
                        float* __restrict__ Y0, float* __restrict__ Y1) {
  const int e = blockIdx.z >> 1, khalf = blockIdx.z & 1;
  const int nt = blockIdx.x, mt = blockIdx.y;
  const int cnt = counts[e];
  if (mt * 128 >= cnt) return;
  const int row0 = offs[e] + mt * 128;
  const int mrem = cnt - mt * 128;
  const int n0 = nt * 128;
  float* __restrict__ Y = khalf ? Y1 : Y0;

  __shared__ u16 As[2][128 * BK];
  __shared__ u16 Bs[2][128 * BK];

  const int tid = threadIdx.x;
  const int lane = tid & 63, wave = tid >> 6;
  const int wm = (wave >> 1) << 6, wn = (wave & 1) << 6;
  const int l16 = lane & 15, quad = lane >> 4;

  const int srow = wave * 32 + (lane >> 2);
  const int scol = (((lane & 3) ^ ((lane >> 3) & 3)) << 3);  // pre-swizzled k-seg
  const int ld0 = wave * 1024;

  const u16* pA = H + (size_t)(row0 + srow) * D_FF + khalf * 2048 + scol;
  const u16* pB = w3t + (size_t)e * D_FF * D_MODEL
                + (size_t)(n0 + srow) * D_FF + khalf * 2048 + scol;
  const size_t rstepA = (size_t)16 * D_FF;

  const int rslot = ((quad ^ ((l16 >> 1) & 3)) << 3);

  f32x4 acc[4][4] = {};

  gll16(pA,           &As[0][ld0]);
  gll16(pA + rstepA,  &As[0][ld0 + 512]);
  gll16(pB,           &Bs[0][ld0]);
  gll16(pB + rstepA,  &Bs[0][ld0 + 512]);
  pA += BK; pB += BK;

  #pragma unroll 2
  for (int ks = 0; ks < 64; ks++) {
    const int c = ks & 1;
    if (ks < 63) {
      gll16(pA,          &As[1 - c][ld0]);
      gll16(pA + rstepA, &As[1 - c][ld0 + 512]);
      gll16(pB,          &Bs[1 - c][ld0]);
      gll16(pB + rstepA, &Bs[1 - c][ld0 + 512]);
      pA += BK; pB += BK;
      asm volatile("s_waitcnt vmcnt(4)" ::: "memory");
    } else {
      asm volatile("s_waitcnt vmcnt(0)" ::: "memory");
    }
    __builtin_amdgcn_sched_barrier(0);
    __builtin_amdgcn_s_barrier();
    __builtin_amdgcn_sched_barrier(0);

    bfrag b[4];
    #pragma unroll
    for (int j = 0; j < 4; j++)
      b[j] = *(const bfrag*)&Bs[c][(wn + j * 16 + l16) * BK + rslot];
    #pragma unroll
    for (int i = 0; i < 4; i++) {
      bfrag a = *(const bfrag*)&As[c][(wm + i * 16 + l16) * BK + rslot];
      #pragma unroll
      for (int j = 0; j < 4; j++)
        acc[i][j] = __builtin_amdgcn_mfma_f32_16x16x32_bf16(a, b[j], acc[i][j], 0, 0, 0);
    }
    __builtin_amdgcn_sched_barrier(0);
    asm volatile("s_waitcnt lgkmcnt(0)" ::: "memory");
    __builtin_amdgcn_s_barrier();
    __builtin_amdgcn_sched_barrier(0);
  }

  #pragma unroll
  for (int i = 0; i < 4; i++) {
    #pragma unroll
    for (int p = 0; p < 4; p++) {
      const int mloc = wm + i * 16 + quad * 4 + p;
      if (mloc < mrem) {
        float* dst = Y + (size_t)(row0 + mloc) * D_MODEL + n0 + wn + l16;
        #pragma unroll
        for (int j = 0; j < 4; j++) dst[j * 16] = acc[i][j][p];
      }
    }
  }
}

// ---------------- combine: out[tok] = sum_j w_j * (Y0+Y1)[arow] ----------
__global__ void k_combine(const float* __restrict__ Y0, const float* __restrict__ Y1,
                          const int* __restrict__ arow, const float* __restrict__ ew,
                          float* __restrict__ out) {
  const int tk = blockIdx.x;
  const int d = threadIdx.x * 4;
  const int a0 = tk * 2, a1 = tk * 2 + 1;
  const int r0 = arow[a0], r1 = arow[a1];
  const float w0 = ew[a0], w1 = ew[a1];
  const float4 p0 = *(const float4*)(Y0 + (size_t)r0 * D_MODEL + d);
  const float4 q0 = *(const float4*)(Y1 + (size_t)r0 * D_MODEL + d);
  const float4 p1 = *(const float4*)(Y0 + (size_t)r1 * D_MODEL + d);
  const float4 q1 = *(const float4*)(Y1 + (size_t)r1 * D_MODEL + d);
  float4 r;
  r.x = w0 * (p0.x + q0.x) + w1 * (p1.x + q1.x);
  r.y = w0 * (p0.y + q0.y) + w1 * (p1.y + q1.y);
  r.z = w0 * (p0.z + q0.z) + w1 * (p1.z + q1.z);
  r.w = w0 * (p0.w + q0.w) + w1 * (p1.w + q1.w);
  *(float4*)(out + (size_t)tk * D_MODEL + d) = r;
}

// ---------------- launcher ----------------
extern "C" void kernel_launch(void* const* d_in, const int* in_sizes, int n_in,
                              void* d_out, int out_size, void* d_ws, size_t ws_size,
                              hipStream_t stream) {
  const float* x  = (const float*)d_in[0];
  const int* eidx = (const int*)d_in[1];
  const float* ew = (const float*)d_in[2];
  const float* w1 = (const float*)d_in[3];
  const float* w2 = (const float*)d_in[4];
  const float* w3 = (const float*)d_in[5];
  float* out = (float*)d_out;

  char* ws = (char*)d_ws;
  int*   rowmap = (int*)(ws);
  int*   arow   = (int*)(ws + 16384);
  int*   counts = (int*)(ws + 32768);
  int*   offs   = (int*)(ws + 32768 + 64);
  const size_t D0 = 65536;
  const size_t SZ_XG = (size_t)ROWS * D_MODEL * 2;            //  8,650,752
  const size_t SZ_HB = (size_t)ROWS * D_FF * 2;               // 34,603,008
  const size_t SZ_Y  = (size_t)ROWS * D_MODEL * 4;            // 17,301,504
  const size_t SZ_W  = (size_t)N_EXPERTS * D_MODEL * D_FF * 2; // 67,108,864
  u16*   Xg  = (u16*)(ws + D0);
  u16*   Hb  = (u16*)(ws + D0 + SZ_XG);
  float* Y0  = (float*)(ws + D0 + SZ_XG + SZ_HB);
  float* Y1  = (float*)(ws + D0 + SZ_XG + SZ_HB + SZ_Y);
  u16*   wt1 = (u16*)(ws + D0 + SZ_XG + SZ_HB + 2 * SZ_Y);
  u16*   wt2 = wt1 + SZ_W / 2;
  u16*   wt3 = wt1;   // aliases wt1: w1t is dead once k_gemm1 completes
  // total ws use ~212 MB

  k_setup<<<1, 256, 0, stream>>>(eidx, ew, rowmap, arow, counts, offs);
  k_gather<<<ROWS, 256, 0, stream>>>(x, rowmap, Xg);
  // pre-convert weights fp32 [K][N] -> bf16 [N][K] (transposed) so GEMMs
  // can stage B with global_load_lds and keep the K-loop free of VALU work.
  k_convt<<<dim3(1024, N_EXPERTS), 256, 0, stream>>>(w1, wt1, D_MODEL, D_FF);
  k_convt<<<dim3(1024, N_EXPERTS), 256, 0, stream>>>(w2, wt2, D_MODEL, D_FF);
  // nt-major grids: blocks sharing a weight slice differ by a multiple of 8
  // in linear index -> same XCD -> weight re-reads are L2 hits.
  k_gemm1<<<dim3(D_FF / 128, 32, N_EXPERTS), 256, 0, stream>>>(Xg, wt1, wt2, counts, offs, Hb);
  k_convt<<<dim3(1024, N_EXPERTS), 256, 0, stream>>>(w3, wt3, D_FF, D_MODEL);
  k_gemm2<<<dim3(D_MODEL / 128, 32, N_EXPERTS * 2), 256, 0, stream>>>(Hb, wt3, counts, offs, Y0, Y1);
  k_combine<<<N_TOKENS, 256, 0, stream>>>(Y0, Y1, arow, ew, out);
}